// Round 9
// baseline (368.467 us; speedup 1.0000x reference)
//
#include <hip/hip_runtime.h>
#include <math.h>

#define LEAKY 0.01f

using short8   = __attribute__((ext_vector_type(8))) short;
using f32x4    = __attribute__((ext_vector_type(4))) float;
using ushort4e = __attribute__((ext_vector_type(4))) unsigned short;

__device__ __forceinline__ ushort f2bf(float f) {
  uint u = __float_as_uint(f);
  uint r = (u + 0x7FFFu + ((u >> 16) & 1u)) >> 16;
  return (ushort)r;
}
__device__ __forceinline__ float bf2f(ushort h) {
  uint u = ((uint)h) << 16;
  return __uint_as_float(u);
}

// ---------------- degree / CSR build ----------------

__global__ void k_zero_i(int* __restrict__ p, int n) {
  int i = blockIdx.x * blockDim.x + threadIdx.x;
  if (i < n) p[i] = 0;
}

__global__ void k_count(const int* __restrict__ dst, int* __restrict__ cnt, int E) {
  int i = blockIdx.x * blockDim.x + threadIdx.x;
  if (i < E) atomicAdd(&cnt[dst[i]], 1);
}

// single block, 1024 threads; N <= 16384. Also emits dinv = rsqrt(cnt+1).
__global__ void k_scan(const int* __restrict__ cnt, int* __restrict__ rowstart,
                       int* __restrict__ cursor, float* __restrict__ dinv,
                       int N, int Etot) {
  __shared__ int part[1024];
  const int t = threadIdx.x;
  const int CH = 16;
  int base = t * CH;
  int local[CH];
  int s = 0;
#pragma unroll
  for (int i = 0; i < CH; i++) {
    int v = (base + i < N) ? cnt[base + i] : 0;
    if (base + i < N) dinv[base + i] = rsqrtf((float)v + 1.0f);
    local[i] = s;
    s += v;
  }
  part[t] = s;
  __syncthreads();
  for (int off = 1; off < 1024; off <<= 1) {
    int add = (t >= off) ? part[t - off] : 0;
    __syncthreads();
    part[t] += add;
    __syncthreads();
  }
  int excl = (t == 0) ? 0 : part[t - 1];
#pragma unroll
  for (int i = 0; i < CH; i++) {
    if (base + i < N) {
      int rs = excl + local[i];
      rowstart[base + i] = rs;
      cursor[base + i] = rs;
    }
  }
  if (t == 0) rowstart[N] = Etot;
}

__global__ void k_csr(const int* __restrict__ src, const int* __restrict__ dst,
                      int* __restrict__ cursor, int* __restrict__ esrc, int E) {
  int i = blockIdx.x * blockDim.x + threadIdx.x;
  if (i < E) {
    int d = dst[i];
    int pos = atomicAdd(&cursor[d], 1);
    esrc[pos] = src[i];
  }
}

// ---------------- W -> [hi|lo|hi] transposed split, both layers in one launch ----------------
__global__ void k_split_w(const float* __restrict__ W1, ushort* __restrict__ Wt1,
                          int K1, int N1,
                          const float* __restrict__ W2, ushort* __restrict__ Wt2,
                          int K2, int N2) {
  int i = blockIdx.x * blockDim.x + threadIdx.x;
  int t1 = K1 * N1;
  if (i < t1) {
    int k = i / N1, n = i % N1;
    float v = W1[i];
    ushort hi = f2bf(v);
    ushort lo = f2bf(v - bf2f(hi));
    ushort* row = Wt1 + (long)n * 3 * K1;
    row[k] = hi; row[K1 + k] = lo; row[2 * K1 + k] = hi;
  } else if (i < t1 + K2 * N2) {
    int j = i - t1;
    int k = j / N2, n = j % N2;
    float v = W2[j];
    ushort hi = f2bf(v);
    ushort lo = f2bf(v - bf2f(hi));
    ushort* row = Wt2 + (long)n * 3 * K2;
    row[k] = hi; row[K2 + k] = lo; row[2 * K2 + k] = hi;
  }
}

// ---------------- gather aggregation (no atomics), bf16 source rows ----------------
template <int F, int VL, bool SPLIT, bool LAST>
__global__ __launch_bounds__(64) void k_agg(const ushort* __restrict__ hlin,
                                            const float* __restrict__ dinv,
                                            const int* __restrict__ rowstart,
                                            const int* __restrict__ esrc,
                                            const float* __restrict__ bias,
                                            ushort* __restrict__ aggb,
                                            float* __restrict__ outh,
                                            ushort* __restrict__ hb, int N) {
  const int node = blockIdx.x;
  const int t = threadIdx.x;
  const float di = dinv[node];
  float acc[VL];
  {
    const ushort* p = hlin + (long)node * F + t * VL;
    if constexpr (VL == 4) {
      ushort4e v = *reinterpret_cast<const ushort4e*>(p);
#pragma unroll
      for (int i = 0; i < 4; i++) acc[i] = bf2f(v[i]) * di * di;
    } else {
      uint v = *reinterpret_cast<const uint*>(p);
      acc[0] = bf2f((ushort)(v & 0xffff)) * di * di;
      acc[1] = bf2f((ushort)(v >> 16)) * di * di;
    }
  }
  const int e0 = rowstart[node], e1 = rowstart[node + 1];
  int e = e0;
  for (; e + 3 < e1; e += 4) {
    int s0 = esrc[e], s1 = esrc[e + 1], s2 = esrc[e + 2], s3 = esrc[e + 3];
    float nm0 = dinv[s0] * di, nm1 = dinv[s1] * di;
    float nm2 = dinv[s2] * di, nm3 = dinv[s3] * di;
    const ushort* p0 = hlin + (long)s0 * F + t * VL;
    const ushort* p1 = hlin + (long)s1 * F + t * VL;
    const ushort* p2 = hlin + (long)s2 * F + t * VL;
    const ushort* p3 = hlin + (long)s3 * F + t * VL;
    if constexpr (VL == 4) {
      ushort4e v0 = *reinterpret_cast<const ushort4e*>(p0);
      ushort4e v1 = *reinterpret_cast<const ushort4e*>(p1);
      ushort4e v2 = *reinterpret_cast<const ushort4e*>(p2);
      ushort4e v3 = *reinterpret_cast<const ushort4e*>(p3);
#pragma unroll
      for (int i = 0; i < 4; i++)
        acc[i] += bf2f(v0[i]) * nm0 + bf2f(v1[i]) * nm1 +
                  bf2f(v2[i]) * nm2 + bf2f(v3[i]) * nm3;
    } else {
      uint v0 = *reinterpret_cast<const uint*>(p0);
      uint v1 = *reinterpret_cast<const uint*>(p1);
      uint v2 = *reinterpret_cast<const uint*>(p2);
      uint v3 = *reinterpret_cast<const uint*>(p3);
      acc[0] += bf2f((ushort)(v0 & 0xffff)) * nm0 + bf2f((ushort)(v1 & 0xffff)) * nm1 +
                bf2f((ushort)(v2 & 0xffff)) * nm2 + bf2f((ushort)(v3 & 0xffff)) * nm3;
      acc[1] += bf2f((ushort)(v0 >> 16)) * nm0 + bf2f((ushort)(v1 >> 16)) * nm1 +
                bf2f((ushort)(v2 >> 16)) * nm2 + bf2f((ushort)(v3 >> 16)) * nm3;
    }
  }
  for (; e < e1; e++) {
    int s0 = esrc[e];
    float nm0 = dinv[s0] * di;
    const ushort* p0 = hlin + (long)s0 * F + t * VL;
    if constexpr (VL == 4) {
      ushort4e v0 = *reinterpret_cast<const ushort4e*>(p0);
#pragma unroll
      for (int i = 0; i < 4; i++) acc[i] += bf2f(v0[i]) * nm0;
    } else {
      uint v0 = *reinterpret_cast<const uint*>(p0);
      acc[0] += bf2f((ushort)(v0 & 0xffff)) * nm0;
      acc[1] += bf2f((ushort)(v0 >> 16)) * nm0;
    }
  }
#pragma unroll
  for (int i = 0; i < VL; i++) {
    float v = acc[i] + bias[t * VL + i];
    v = (v > 0.f) ? v : (LEAKY * v);
    int f = t * VL + i;
    if constexpr (SPLIT) {
      ushort hi = f2bf(v);
      ushort lo = f2bf(v - bf2f(hi));
      ushort* row = aggb + (long)node * 3 * F;
      row[f] = hi;
      row[F + f] = hi;
      row[2 * F + f] = lo;
    }
    if constexpr (LAST) {
      long idx = (long)node * F + f;
      outh[idx] = v;
      hb[idx] = f2bf(v);
    }
  }
}

// ---------------- layer-1 GEMM: h1b = bf16( x @ W1 ), fused in-register x split ----------------
template <int CPR>
__global__ __launch_bounds__(256) void k_gemm_x(const float* __restrict__ X,
                                                const ushort* __restrict__ Bb,
                                                ushort* __restrict__ Cb,
                                                int M, int Nc, int Kreal) {
  __shared__ __align__(16) ushort lds[2 * 128 * 128];
  ushort* ldsA = lds;
  ushort* ldsB = lds + 128 * 128;

  const int tid = threadIdx.x;
  const int lane = tid & 63;
  const int wv = tid >> 6;
  const int wr = wv >> 1, wc = wv & 1;
  const long bm = (long)blockIdx.y * 128;
  const long bn = (long)blockIdx.x * 128;
  const int Kp = 3 * Kreal;

  f32x4 acc[4][4];
#pragma unroll
  for (int i = 0; i < 4; i++)
#pragma unroll
    for (int j = 0; j < 4; j++) acc[i][j] = (f32x4){0.f, 0.f, 0.f, 0.f};

  const int kb = ((lane >> 4) << 4);

  for (int c = 0; c < 3 * CPR; c++) {
    const int region = c / CPR;
    const int sc = (c % CPR) * 128;
#pragma unroll
    for (int it = 0; it < 16; it++) {
      int idx = it * 1024 + tid * 4;
      int row = idx >> 7, col = idx & 127;
      long gr = bm + row;
      float4 xv = make_float4(0.f, 0.f, 0.f, 0.f);
      if (gr < M) xv = *reinterpret_cast<const float4*>(&X[gr * Kreal + sc + col]);
      float vv[4] = {xv.x, xv.y, xv.z, xv.w};
      ushort4e u;
#pragma unroll
      for (int j = 0; j < 4; j++) {
        ushort hi = f2bf(vv[j]);
        u[j] = (region < 2) ? hi : f2bf(vv[j] - bf2f(hi));
      }
      int b = (row << 8) | ((col * 2) ^ ((row & 7) << 4));
      *reinterpret_cast<ushort4e*>((char*)ldsA + b) = u;
    }
#pragma unroll
    for (int it = 0; it < 8; it++) {
      int off = it * 4096 + tid * 16;
      int row = off >> 8;
      int cb = off & 255;
      long gn = bn + row;
      uint4 v = make_uint4(0u, 0u, 0u, 0u);
      if (gn < Nc)
        v = *reinterpret_cast<const uint4*>(&Bb[gn * Kp + c * 128 + (cb >> 1)]);
      int sb = (row << 8) | (cb ^ ((row & 7) << 4));
      *reinterpret_cast<uint4*>((char*)ldsB + sb) = v;
    }
    __syncthreads();

#pragma unroll
    for (int ks = 0; ks < 4; ks++) {
      short8 af[4], bfr[4];
#pragma unroll
      for (int mi = 0; mi < 4; mi++) {
        int row = wr * 64 + mi * 16 + (lane & 15);
        int b = ks * 64 + kb;
        int addr = (row << 8) | (b ^ ((row & 7) << 4));
        af[mi] = *reinterpret_cast<const short8*>((const char*)ldsA + addr);
      }
#pragma unroll
      for (int ni = 0; ni < 4; ni++) {
        int row = wc * 64 + ni * 16 + (lane & 15);
        int b = ks * 64 + kb;
        int addr = (row << 8) | (b ^ ((row & 7) << 4));
        bfr[ni] = *reinterpret_cast<const short8*>((const char*)ldsB + addr);
      }
#pragma unroll
      for (int mi = 0; mi < 4; mi++)
#pragma unroll
        for (int ni = 0; ni < 4; ni++)
          acc[mi][ni] = __builtin_amdgcn_mfma_f32_16x16x32_bf16(af[mi], bfr[ni], acc[mi][ni], 0, 0, 0);
    }
    __syncthreads();
  }

#pragma unroll
  for (int ni = 0; ni < 4; ni++) {
    long col = bn + wc * 64 + ni * 16 + (lane & 15);
    if (col >= Nc) continue;
#pragma unroll
    for (int mi = 0; mi < 4; mi++) {
      long rbase2 = bm + wr * 64 + mi * 16 + ((lane >> 4) << 2);
#pragma unroll
      for (int j = 0; j < 4; j++) {
        long row = rbase2 + j;
        if (row >= M) continue;
        Cb[row * Nc + col] = f2bf(acc[mi][ni][j]);
      }
    }
  }
}

// ---------------- bf16 MFMA GEMM-BT, templated BM, bf16 out ----------------
template <int BM>
__global__ __launch_bounds__(256) void k_gemm_bt(const ushort* __restrict__ Ab,
                                                 const ushort* __restrict__ Bb,
                                                 ushort* __restrict__ Cb,
                                                 int M, int N, int K, int ldc) {
  constexpr int MI = BM / 32;
  __shared__ __align__(16) ushort lds[(BM + 128) * 128];
  ushort* ldsA = lds;
  ushort* ldsB = lds + BM * 128;

  const int tid = threadIdx.x;
  const int lane = tid & 63;
  const int wv = tid >> 6;
  const int wr = wv >> 1, wc = wv & 1;
  const long bm = (long)blockIdx.y * BM;
  const long bn = (long)blockIdx.x * 128;

  f32x4 acc[MI][4];
#pragma unroll
  for (int i = 0; i < MI; i++)
#pragma unroll
    for (int j = 0; j < 4; j++) acc[i][j] = (f32x4){0.f, 0.f, 0.f, 0.f};

  const int kb = ((lane >> 4) << 4);

  for (int k0 = 0; k0 < K; k0 += 128) {
#pragma unroll
    for (int it = 0; it < BM / 16; it++) {
      int off = it * 4096 + tid * 16;
      int row = off >> 8;
      int cb = off & 255;
      long gr = bm + row;
      uint4 v = make_uint4(0u, 0u, 0u, 0u);
      if (gr < M) v = *reinterpret_cast<const uint4*>(&Ab[gr * K + k0 + (cb >> 1)]);
      int sb = (row << 8) | (cb ^ ((row & 7) << 4));
      *reinterpret_cast<uint4*>((char*)ldsA + sb) = v;
    }
#pragma unroll
    for (int it = 0; it < 8; it++) {
      int off = it * 4096 + tid * 16;
      int row = off >> 8;
      int cb = off & 255;
      long gn = bn + row;
      uint4 v = make_uint4(0u, 0u, 0u, 0u);
      if (gn < N) v = *reinterpret_cast<const uint4*>(&Bb[gn * K + k0 + (cb >> 1)]);
      int sb = (row << 8) | (cb ^ ((row & 7) << 4));
      *reinterpret_cast<uint4*>((char*)ldsB + sb) = v;
    }
    __syncthreads();

#pragma unroll
    for (int ks = 0; ks < 4; ks++) {
      short8 af[MI], bfr[4];
#pragma unroll
      for (int mi = 0; mi < MI; mi++) {
        int row = wr * (BM / 2) + mi * 16 + (lane & 15);
        int b = ks * 64 + kb;
        int addr = (row << 8) | (b ^ ((row & 7) << 4));
        af[mi] = *reinterpret_cast<const short8*>((const char*)ldsA + addr);
      }
#pragma unroll
      for (int ni = 0; ni < 4; ni++) {
        int row = wc * 64 + ni * 16 + (lane & 15);
        int b = ks * 64 + kb;
        int addr = (row << 8) | (b ^ ((row & 7) << 4));
        bfr[ni] = *reinterpret_cast<const short8*>((const char*)ldsB + addr);
      }
#pragma unroll
      for (int mi = 0; mi < MI; mi++)
#pragma unroll
        for (int ni = 0; ni < 4; ni++)
          acc[mi][ni] = __builtin_amdgcn_mfma_f32_16x16x32_bf16(af[mi], bfr[ni], acc[mi][ni], 0, 0, 0);
    }
    __syncthreads();
  }

#pragma unroll
  for (int ni = 0; ni < 4; ni++) {
    long col = bn + wc * 64 + ni * 16 + (lane & 15);
    if (col >= N) continue;
#pragma unroll
    for (int mi = 0; mi < MI; mi++) {
      long rbase2 = bm + wr * (BM / 2) + mi * 16 + ((lane >> 4) << 2);
#pragma unroll
      for (int j = 0; j < 4; j++) {
        long row = rbase2 + j;
        if (row >= M) continue;
        Cb[row * ldc + col] = f2bf(acc[mi][ni][j]);
      }
    }
  }
}

// ---------------- symmetric decode: x1 = sigmoid(H H^T), H [N,128] bf16 ----------------
// Triangular grid. Stores are PLAIN (via L2): full-64B-line coverage per instruction
// avoids RFO (proof: harness fills hit 6.8 TB/s, FETCH~0); nt bypassed L2 and capped BW.
__global__ __launch_bounds__(256) void k_decode_sym(const ushort* __restrict__ Hb,
                                                    float* __restrict__ C, int N) {
  __shared__ __align__(16) ushort lds[2 * 128 * 128];
  ushort* ldsA = lds;
  ushort* ldsB = lds + 128 * 128;

  const int tid = threadIdx.x;
  const int lane = tid & 63;
  const int wv = tid >> 6;
  const int wr = wv >> 1, wc = wv & 1;

  int t = blockIdx.x;
  int bi = (int)((sqrtf(8.f * (float)t + 1.f) - 1.f) * 0.5f);
  while ((bi + 1) * (bi + 2) / 2 <= t) bi++;
  while (bi * (bi + 1) / 2 > t) bi--;
  int bj = t - bi * (bi + 1) / 2;
  const long bm = (long)bi * 128;
  const long bn = (long)bj * 128;

#pragma unroll
  for (int s = 0; s < 2; s++) {
    long rbase = s ? bn : bm;
    ushort* L = s ? ldsB : ldsA;
#pragma unroll
    for (int it = 0; it < 8; it++) {
      int off = it * 4096 + tid * 16;
      int row = off >> 8;
      int cb = off & 255;
      long grow = rbase + row;
      uint4 v = make_uint4(0u, 0u, 0u, 0u);
      if (grow < N)
        v = *reinterpret_cast<const uint4*>(&Hb[grow * 128 + (cb >> 1)]);
      int sb = (row << 8) | (cb ^ ((row & 7) << 4));
      *reinterpret_cast<uint4*>((char*)L + sb) = v;
    }
  }
  __syncthreads();

  f32x4 acc[4][4];
#pragma unroll
  for (int i = 0; i < 4; i++)
#pragma unroll
    for (int j = 0; j < 4; j++) acc[i][j] = (f32x4){0.f, 0.f, 0.f, 0.f};

  const int kb = ((lane >> 4) << 4);
#pragma unroll
  for (int ks = 0; ks < 4; ks++) {
    short8 af[4], bfr[4];
#pragma unroll
    for (int mi = 0; mi < 4; mi++) {
      int row = wr * 64 + mi * 16 + (lane & 15);
      int b = ks * 64 + kb;
      int addr = (row << 8) | (b ^ ((row & 7) << 4));
      af[mi] = *reinterpret_cast<const short8*>((const char*)ldsA + addr);
    }
#pragma unroll
    for (int ni = 0; ni < 4; ni++) {
      int row = wc * 64 + ni * 16 + (lane & 15);
      int b = ks * 64 + kb;
      int addr = (row << 8) | (b ^ ((row & 7) << 4));
      bfr[ni] = *reinterpret_cast<const short8*>((const char*)ldsB + addr);
    }
#pragma unroll
    for (int mi = 0; mi < 4; mi++)
#pragma unroll
      for (int ni = 0; ni < 4; ni++)
        acc[mi][ni] = __builtin_amdgcn_mfma_f32_16x16x32_bf16(af[mi], bfr[ni], acc[mi][ni], 0, 0, 0);
  }

  // sigmoid once in registers
#pragma unroll
  for (int mi = 0; mi < 4; mi++)
#pragma unroll
    for (int ni = 0; ni < 4; ni++)
#pragma unroll
      for (int j = 0; j < 4; j++)
        acc[mi][ni][j] = __builtin_amdgcn_rcpf(1.f + __expf(-acc[mi][ni][j]));

  // transposed store direct from registers: 16 full 64B lines per instr (plain)
  if (bi != bj) {
#pragma unroll
    for (int ni = 0; ni < 4; ni++) {
      long gr = bn + wc * 64 + ni * 16 + (lane & 15);
#pragma unroll
      for (int mi = 0; mi < 4; mi++) {
        long gc = bm + wr * 64 + mi * 16 + ((lane >> 4) << 2);
        if (gr < N && gc < N)
          *reinterpret_cast<f32x4*>(&C[gr * N + gc]) = acc[mi][ni];
      }
    }
  }

  __syncthreads();

  // normal orientation via LDS bounce, coalesced 512B rows (plain stores)
  float* ft = (float*)lds;
#pragma unroll
  for (int ni = 0; ni < 4; ni++) {
    int col = wc * 64 + ni * 16 + (lane & 15);
#pragma unroll
    for (int mi = 0; mi < 4; mi++) {
      int rb = wr * 64 + mi * 16 + ((lane >> 4) << 2);
#pragma unroll
      for (int j = 0; j < 4; j++) {
        int row = rb + j;
        int byte = (row << 9) + (col << 2);
        byte ^= ((row & 7) << 4);
        *reinterpret_cast<float*>((char*)ft + byte) = acc[mi][ni][j];
      }
    }
  }
  __syncthreads();

#pragma unroll
  for (int it = 0; it < 16; it++) {
    int r = (tid >> 5) + it * 8;
    int ch = tid & 31;
    int byte = (r << 9) + (ch << 4);
    byte ^= ((r & 7) << 4);
    f32x4 v = *reinterpret_cast<const f32x4*>((const char*)ft + byte);
    long gr = bm + r;
    long gc = bn + ch * 4;
    if (gr < N && gc < N)
      *reinterpret_cast<f32x4*>(&C[gr * N + gc]) = v;
  }
}

// ---------------- launch ----------------

extern "C" void kernel_launch(void* const* d_in, const int* in_sizes, int n_in,
                              void* d_out, int out_size, void* d_ws, size_t ws_size,
                              hipStream_t stream) {
  const float* x  = (const float*)d_in[0];
  const int*   ei = (const int*)d_in[1];
  const float* W1 = (const float*)d_in[3];
  const float* b1 = (const float*)d_in[4];
  const float* W2 = (const float*)d_in[5];
  const float* b2 = (const float*)d_in[6];

  const int N   = in_sizes[2];          // 10000
  const int E   = in_sizes[1] / 2;      // 320000
  const int Fin = in_sizes[0] / N;      // 512
  const int F1  = in_sizes[4];          // 256
  const int F2  = in_sizes[6];          // 128

  const int* src = ei;
  const int* dst = ei + E;

  float* ws = (float*)d_ws;
  ushort* w1t3     = (ushort*)ws;                    // F1*3*Fin ush
  ushort* w2t3     = (ushort*)(ws + 196608);         // F2*3*F1 ush
  ushort* h1b      = (ushort*)(ws + 245760);         // N*F1 ush
  ushort* agg1b3   = (ushort*)(ws + 1525760);        // N*3*F1 ush
  ushort* h2b      = (ushort*)(ws + 5365760);        // N*F2 ush
  ushort* hb       = (ushort*)(ws + 6005760);        // N*F2 ush
  float*  dinv     = ws + 6645760;                   // N
  int*    cnt      = (int*)(ws + 6656000);           // N
  int*    cursor   = (int*)(ws + 6666240);           // N
  int*    rowstart = (int*)(ws + 6676480);           // N+1
  int*    esrc     = (int*)(ws + 6686976);           // E

  float* out_x1 = (float*)d_out;
  float* out_h  = out_x1 + (long)N * N;

  // CSR build + dinv
  k_zero_i<<<(N + 255) / 256, 256, 0, stream>>>(cnt, N);
  k_count<<<(E + 255) / 256, 256, 0, stream>>>(dst, cnt, E);
  k_scan<<<1, 1024, 0, stream>>>(cnt, rowstart, cursor, dinv, N, E);
  k_csr<<<(E + 255) / 256, 256, 0, stream>>>(src, dst, cursor, esrc, E);

  // weight splits (both layers, one launch)
  {
    int tot = Fin * F1 + F1 * F2;
    k_split_w<<<(tot + 255) / 256, 256, 0, stream>>>(W1, w1t3, Fin, F1,
                                                     W2, w2t3, F1, F2);
  }

  // layer 1: h1b = bf16( x @ W1 ), fused in-register split of x, K' = 1536
  {
    dim3 grid(F1 / 128, (N + 127) / 128);
    k_gemm_x<4><<<grid, 256, 0, stream>>>(x, w1t3, h1b, N, F1, Fin);
  }
  k_agg<256, 4, true, false><<<N, 64, 0, stream>>>(h1b, dinv, rowstart, esrc, b1,
                                                   agg1b3, nullptr, nullptr, N);

  // layer 2: h2b = bf16( agg1 @ W2 ), K' = 768, BM=64 for parallelism
  {
    dim3 grid(F2 / 128, (N + 63) / 64);
    k_gemm_bt<64><<<grid, 256, 0, stream>>>(agg1b3, w2t3, h2b, N, F2, 3 * F1, F2);
  }
  k_agg<128, 2, false, true><<<N, 64, 0, stream>>>(h2b, dinv, rowstart, esrc, b2,
                                                   nullptr, out_h, hb, N);

  // decode: x1 = sigmoid(h @ h^T), symmetric triangular grid
  {
    int NB = (N + 127) / 128;
    int nblk = NB * (NB + 1) / 2;
    k_decode_sym<<<nblk, 256, 0, stream>>>(hb, out_x1, N);
  }
}

// Round 10
// 252.451 us; speedup vs baseline: 1.4596x; 1.4596x over previous
//
#include <hip/hip_runtime.h>
#include <math.h>

#define LEAKY 0.01f

using short8   = __attribute__((ext_vector_type(8))) short;
using f32x4    = __attribute__((ext_vector_type(4))) float;
using ushort4e = __attribute__((ext_vector_type(4))) unsigned short;

__device__ __forceinline__ ushort f2bf(float f) {
  uint u = __float_as_uint(f);
  uint r = (u + 0x7FFFu + ((u >> 16) & 1u)) >> 16;
  return (ushort)r;
}
__device__ __forceinline__ float bf2f(ushort h) {
  uint u = ((uint)h) << 16;
  return __uint_as_float(u);
}

// ---------------- degree / CSR build ----------------

__global__ void k_zero_i(int* __restrict__ p, int n) {
  int i = blockIdx.x * blockDim.x + threadIdx.x;
  if (i < n) p[i] = 0;
}

__global__ void k_count(const int* __restrict__ dst, int* __restrict__ cnt, int E) {
  int i = blockIdx.x * blockDim.x + threadIdx.x;
  if (i < E) atomicAdd(&cnt[dst[i]], 1);
}

// single block, 1024 threads; N <= 16384. Also emits dinv = rsqrt(cnt+1).
__global__ void k_scan(const int* __restrict__ cnt, int* __restrict__ rowstart,
                       int* __restrict__ cursor, float* __restrict__ dinv,
                       int N, int Etot) {
  __shared__ int part[1024];
  const int t = threadIdx.x;
  const int CH = 16;
  int base = t * CH;
  int local[CH];
  int s = 0;
#pragma unroll
  for (int i = 0; i < CH; i++) {
    int v = (base + i < N) ? cnt[base + i] : 0;
    if (base + i < N) dinv[base + i] = rsqrtf((float)v + 1.0f);
    local[i] = s;
    s += v;
  }
  part[t] = s;
  __syncthreads();
  for (int off = 1; off < 1024; off <<= 1) {
    int add = (t >= off) ? part[t - off] : 0;
    __syncthreads();
    part[t] += add;
    __syncthreads();
  }
  int excl = (t == 0) ? 0 : part[t - 1];
#pragma unroll
  for (int i = 0; i < CH; i++) {
    if (base + i < N) {
      int rs = excl + local[i];
      rowstart[base + i] = rs;
      cursor[base + i] = rs;
    }
  }
  if (t == 0) rowstart[N] = Etot;
}

__global__ void k_csr(const int* __restrict__ src, const int* __restrict__ dst,
                      int* __restrict__ cursor, int* __restrict__ esrc, int E) {
  int i = blockIdx.x * blockDim.x + threadIdx.x;
  if (i < E) {
    int d = dst[i];
    int pos = atomicAdd(&cursor[d], 1);
    esrc[pos] = src[i];
  }
}

// ---------------- conversions: x -> bf16, W -> transposed bf16 ----------------

__global__ void k_xb(const float* __restrict__ X, ushort* __restrict__ Xb, long total) {
  long i = ((long)blockIdx.x * blockDim.x + threadIdx.x) * 4;
  if (i < total) {
    float4 v = *reinterpret_cast<const float4*>(&X[i]);
    ushort4e u = {f2bf(v.x), f2bf(v.y), f2bf(v.z), f2bf(v.w)};
    *reinterpret_cast<ushort4e*>(&Xb[i]) = u;
  }
}

__global__ void k_wt(const float* __restrict__ W1, ushort* __restrict__ Wt1,
                     int K1, int N1,
                     const float* __restrict__ W2, ushort* __restrict__ Wt2,
                     int K2, int N2) {
  int i = blockIdx.x * blockDim.x + threadIdx.x;
  int t1 = K1 * N1;
  if (i < t1) {
    int k = i / N1, n = i % N1;
    Wt1[(long)n * K1 + k] = f2bf(W1[i]);
  } else if (i < t1 + K2 * N2) {
    int j = i - t1;
    int k = j / N2, n = j % N2;
    Wt2[(long)n * K2 + k] = f2bf(W2[j]);
  }
}

// ---------------- gather aggregation (no atomics), bf16 in / bf16 out ----------------
// one wave per node; F = VL*64 features. fp32 accumulate.
// Writes leaky(agg+bias) as bf16 to aggb; LAST also writes fp32 to outh.
template <int F, int VL, bool LAST>
__global__ __launch_bounds__(64) void k_agg(const ushort* __restrict__ hlin,
                                            const float* __restrict__ dinv,
                                            const int* __restrict__ rowstart,
                                            const int* __restrict__ esrc,
                                            const float* __restrict__ bias,
                                            ushort* __restrict__ aggb,
                                            float* __restrict__ outh, int N) {
  const int node = blockIdx.x;
  const int t = threadIdx.x;
  const float di = dinv[node];
  float acc[VL];
  {
    const ushort* p = hlin + (long)node * F + t * VL;
    if constexpr (VL == 4) {
      ushort4e v = *reinterpret_cast<const ushort4e*>(p);
#pragma unroll
      for (int i = 0; i < 4; i++) acc[i] = bf2f(v[i]) * di * di;
    } else {
      uint v = *reinterpret_cast<const uint*>(p);
      acc[0] = bf2f((ushort)(v & 0xffff)) * di * di;
      acc[1] = bf2f((ushort)(v >> 16)) * di * di;
    }
  }
  const int e0 = rowstart[node], e1 = rowstart[node + 1];
  int e = e0;
  for (; e + 3 < e1; e += 4) {
    int s0 = esrc[e], s1 = esrc[e + 1], s2 = esrc[e + 2], s3 = esrc[e + 3];
    float nm0 = dinv[s0] * di, nm1 = dinv[s1] * di;
    float nm2 = dinv[s2] * di, nm3 = dinv[s3] * di;
    const ushort* p0 = hlin + (long)s0 * F + t * VL;
    const ushort* p1 = hlin + (long)s1 * F + t * VL;
    const ushort* p2 = hlin + (long)s2 * F + t * VL;
    const ushort* p3 = hlin + (long)s3 * F + t * VL;
    if constexpr (VL == 4) {
      ushort4e v0 = *reinterpret_cast<const ushort4e*>(p0);
      ushort4e v1 = *reinterpret_cast<const ushort4e*>(p1);
      ushort4e v2 = *reinterpret_cast<const ushort4e*>(p2);
      ushort4e v3 = *reinterpret_cast<const ushort4e*>(p3);
#pragma unroll
      for (int i = 0; i < 4; i++)
        acc[i] += bf2f(v0[i]) * nm0 + bf2f(v1[i]) * nm1 +
                  bf2f(v2[i]) * nm2 + bf2f(v3[i]) * nm3;
    } else {
      uint v0 = *reinterpret_cast<const uint*>(p0);
      uint v1 = *reinterpret_cast<const uint*>(p1);
      uint v2 = *reinterpret_cast<const uint*>(p2);
      uint v3 = *reinterpret_cast<const uint*>(p3);
      acc[0] += bf2f((ushort)(v0 & 0xffff)) * nm0 + bf2f((ushort)(v1 & 0xffff)) * nm1 +
                bf2f((ushort)(v2 & 0xffff)) * nm2 + bf2f((ushort)(v3 & 0xffff)) * nm3;
      acc[1] += bf2f((ushort)(v0 >> 16)) * nm0 + bf2f((ushort)(v1 >> 16)) * nm1 +
                bf2f((ushort)(v2 >> 16)) * nm2 + bf2f((ushort)(v3 >> 16)) * nm3;
    }
  }
  for (; e < e1; e++) {
    int s0 = esrc[e];
    float nm0 = dinv[s0] * di;
    const ushort* p0 = hlin + (long)s0 * F + t * VL;
    if constexpr (VL == 4) {
      ushort4e v0 = *reinterpret_cast<const ushort4e*>(p0);
#pragma unroll
      for (int i = 0; i < 4; i++) acc[i] += bf2f(v0[i]) * nm0;
    } else {
      uint v0 = *reinterpret_cast<const uint*>(p0);
      acc[0] += bf2f((ushort)(v0 & 0xffff)) * nm0;
      acc[1] += bf2f((ushort)(v0 >> 16)) * nm0;
    }
  }
#pragma unroll
  for (int i = 0; i < VL; i++) {
    float v = acc[i] + bias[t * VL + i];
    acc[i] = (v > 0.f) ? v : (LEAKY * v);
  }
  if constexpr (VL == 4) {
    ushort4e o = {f2bf(acc[0]), f2bf(acc[1]), f2bf(acc[2]), f2bf(acc[3])};
    *reinterpret_cast<ushort4e*>(&aggb[(long)node * F + t * 4]) = o;
    if constexpr (LAST) {
      float4 fo = make_float4(acc[0], acc[1], acc[2], acc[3]);
      *reinterpret_cast<float4*>(&outh[(long)node * F + t * 4]) = fo;
    }
  } else {
    uint o = (uint)f2bf(acc[0]) | ((uint)f2bf(acc[1]) << 16);
    *reinterpret_cast<uint*>(&aggb[(long)node * F + t * 2]) = o;
    if constexpr (LAST) {
      float2 fo = make_float2(acc[0], acc[1]);
      *reinterpret_cast<float2*>(&outh[(long)node * F + t * 2]) = fo;
    }
  }
}

// ---------------- bf16 MFMA GEMM-BT, templated BM, bf16 out ----------------
// C[M,N] = A[M,K] * B[N,K]^T, A/B bf16 row-major, K mult of 128.
template <int BM>
__global__ __launch_bounds__(256) void k_gemm_bt(const ushort* __restrict__ Ab,
                                                 const ushort* __restrict__ Bb,
                                                 ushort* __restrict__ Cb,
                                                 int M, int N, int K, int ldc) {
  constexpr int MI = BM / 32;
  __shared__ __align__(16) ushort lds[(BM + 128) * 128];
  ushort* ldsA = lds;
  ushort* ldsB = lds + BM * 128;

  const int tid = threadIdx.x;
  const int lane = tid & 63;
  const int wv = tid >> 6;
  const int wr = wv >> 1, wc = wv & 1;
  const long bm = (long)blockIdx.y * BM;
  const long bn = (long)blockIdx.x * 128;

  f32x4 acc[MI][4];
#pragma unroll
  for (int i = 0; i < MI; i++)
#pragma unroll
    for (int j = 0; j < 4; j++) acc[i][j] = (f32x4){0.f, 0.f, 0.f, 0.f};

  const int kb = ((lane >> 4) << 4);

  for (int k0 = 0; k0 < K; k0 += 128) {
#pragma unroll
    for (int it = 0; it < BM / 16; it++) {
      int off = it * 4096 + tid * 16;
      int row = off >> 8;
      int cb = off & 255;
      long gr = bm + row;
      uint4 v = make_uint4(0u, 0u, 0u, 0u);
      if (gr < M) v = *reinterpret_cast<const uint4*>(&Ab[gr * K + k0 + (cb >> 1)]);
      int sb = (row << 8) | (cb ^ ((row & 7) << 4));
      *reinterpret_cast<uint4*>((char*)ldsA + sb) = v;
    }
#pragma unroll
    for (int it = 0; it < 8; it++) {
      int off = it * 4096 + tid * 16;
      int row = off >> 8;
      int cb = off & 255;
      long gn = bn + row;
      uint4 v = make_uint4(0u, 0u, 0u, 0u);
      if (gn < N) v = *reinterpret_cast<const uint4*>(&Bb[gn * K + k0 + (cb >> 1)]);
      int sb = (row << 8) | (cb ^ ((row & 7) << 4));
      *reinterpret_cast<uint4*>((char*)ldsB + sb) = v;
    }
    __syncthreads();

#pragma unroll
    for (int ks = 0; ks < 4; ks++) {
      short8 af[MI], bfr[4];
#pragma unroll
      for (int mi = 0; mi < MI; mi++) {
        int row = wr * (BM / 2) + mi * 16 + (lane & 15);
        int b = ks * 64 + kb;
        int addr = (row << 8) | (b ^ ((row & 7) << 4));
        af[mi] = *reinterpret_cast<const short8*>((const char*)ldsA + addr);
      }
#pragma unroll
      for (int ni = 0; ni < 4; ni++) {
        int row = wc * 64 + ni * 16 + (lane & 15);
        int b = ks * 64 + kb;
        int addr = (row << 8) | (b ^ ((row & 7) << 4));
        bfr[ni] = *reinterpret_cast<const short8*>((const char*)ldsB + addr);
      }
#pragma unroll
      for (int mi = 0; mi < MI; mi++)
#pragma unroll
        for (int ni = 0; ni < 4; ni++)
          acc[mi][ni] = __builtin_amdgcn_mfma_f32_16x16x32_bf16(af[mi], bfr[ni], acc[mi][ni], 0, 0, 0);
    }
    __syncthreads();
  }

#pragma unroll
  for (int ni = 0; ni < 4; ni++) {
    long col = bn + wc * 64 + ni * 16 + (lane & 15);
    if (col >= N) continue;
#pragma unroll
    for (int mi = 0; mi < MI; mi++) {
      long rbase2 = bm + wr * (BM / 2) + mi * 16 + ((lane >> 4) << 2);
#pragma unroll
      for (int j = 0; j < 4; j++) {
        long row = rbase2 + j;
        if (row >= M) continue;
        Cb[row * ldc + col] = f2bf(acc[mi][ni][j]);
      }
    }
  }
}

// ---------------- symmetric decode: x1 = sigmoid(H H^T), H [N,128] bf16 ----------------
// Triangular grid. NT stores with full-64B-line coverage per instruction (R6/R8 lesson).
__global__ __launch_bounds__(256) void k_decode_sym(const ushort* __restrict__ Hb,
                                                    float* __restrict__ C, int N) {
  __shared__ __align__(16) ushort lds[2 * 128 * 128];
  ushort* ldsA = lds;
  ushort* ldsB = lds + 128 * 128;

  const int tid = threadIdx.x;
  const int lane = tid & 63;
  const int wv = tid >> 6;
  const int wr = wv >> 1, wc = wv & 1;

  int t = blockIdx.x;
  int bi = (int)((sqrtf(8.f * (float)t + 1.f) - 1.f) * 0.5f);
  while ((bi + 1) * (bi + 2) / 2 <= t) bi++;
  while (bi * (bi + 1) / 2 > t) bi--;
  int bj = t - bi * (bi + 1) / 2;
  const long bm = (long)bi * 128;
  const long bn = (long)bj * 128;

#pragma unroll
  for (int s = 0; s < 2; s++) {
    long rbase = s ? bn : bm;
    ushort* L = s ? ldsB : ldsA;
#pragma unroll
    for (int it = 0; it < 8; it++) {
      int off = it * 4096 + tid * 16;
      int row = off >> 8;
      int cb = off & 255;
      long grow = rbase + row;
      uint4 v = make_uint4(0u, 0u, 0u, 0u);
      if (grow < N)
        v = *reinterpret_cast<const uint4*>(&Hb[grow * 128 + (cb >> 1)]);
      int sb = (row << 8) | (cb ^ ((row & 7) << 4));
      *reinterpret_cast<uint4*>((char*)L + sb) = v;
    }
  }
  __syncthreads();

  f32x4 acc[4][4];
#pragma unroll
  for (int i = 0; i < 4; i++)
#pragma unroll
    for (int j = 0; j < 4; j++) acc[i][j] = (f32x4){0.f, 0.f, 0.f, 0.f};

  const int kb = ((lane >> 4) << 4);
#pragma unroll
  for (int ks = 0; ks < 4; ks++) {
    short8 af[4], bfr[4];
#pragma unroll
    for (int mi = 0; mi < 4; mi++) {
      int row = wr * 64 + mi * 16 + (lane & 15);
      int b = ks * 64 + kb;
      int addr = (row << 8) | (b ^ ((row & 7) << 4));
      af[mi] = *reinterpret_cast<const short8*>((const char*)ldsA + addr);
    }
#pragma unroll
    for (int ni = 0; ni < 4; ni++) {
      int row = wc * 64 + ni * 16 + (lane & 15);
      int b = ks * 64 + kb;
      int addr = (row << 8) | (b ^ ((row & 7) << 4));
      bfr[ni] = *reinterpret_cast<const short8*>((const char*)ldsB + addr);
    }
#pragma unroll
    for (int mi = 0; mi < 4; mi++)
#pragma unroll
      for (int ni = 0; ni < 4; ni++)
        acc[mi][ni] = __builtin_amdgcn_mfma_f32_16x16x32_bf16(af[mi], bfr[ni], acc[mi][ni], 0, 0, 0);
  }

  // sigmoid once in registers
#pragma unroll
  for (int mi = 0; mi < 4; mi++)
#pragma unroll
    for (int ni = 0; ni < 4; ni++)
#pragma unroll
      for (int j = 0; j < 4; j++)
        acc[mi][ni][j] = __builtin_amdgcn_rcpf(1.f + __expf(-acc[mi][ni][j]));

  // transposed store direct from registers: 16 full 64B lines per instr
  if (bi != bj) {
#pragma unroll
    for (int ni = 0; ni < 4; ni++) {
      long gr = bn + wc * 64 + ni * 16 + (lane & 15);
#pragma unroll
      for (int mi = 0; mi < 4; mi++) {
        long gc = bm + wr * 64 + mi * 16 + ((lane >> 4) << 2);
        if (gr < N && gc < N)
          __builtin_nontemporal_store(acc[mi][ni],
                                      reinterpret_cast<f32x4*>(&C[gr * N + gc]));
      }
    }
  }

  __syncthreads();

  // normal orientation via LDS bounce, coalesced 512B rows
  float* ft = (float*)lds;
#pragma unroll
  for (int ni = 0; ni < 4; ni++) {
    int col = wc * 64 + ni * 16 + (lane & 15);
#pragma unroll
    for (int mi = 0; mi < 4; mi++) {
      int rb = wr * 64 + mi * 16 + ((lane >> 4) << 2);
#pragma unroll
      for (int j = 0; j < 4; j++) {
        int row = rb + j;
        int byte = (row << 9) + (col << 2);
        byte ^= ((row & 7) << 4);
        *reinterpret_cast<float*>((char*)ft + byte) = acc[mi][ni][j];
      }
    }
  }
  __syncthreads();

#pragma unroll
  for (int it = 0; it < 16; it++) {
    int r = (tid >> 5) + it * 8;
    int ch = tid & 31;
    int byte = (r << 9) + (ch << 4);
    byte ^= ((r & 7) << 4);
    f32x4 v = *reinterpret_cast<const f32x4*>((const char*)ft + byte);
    long gr = bm + r;
    long gc = bn + ch * 4;
    if (gr < N && gc < N)
      __builtin_nontemporal_store(v, reinterpret_cast<f32x4*>(&C[gr * N + gc]));
  }
}

// ---------------- launch ----------------

extern "C" void kernel_launch(void* const* d_in, const int* in_sizes, int n_in,
                              void* d_out, int out_size, void* d_ws, size_t ws_size,
                              hipStream_t stream) {
  const float* x  = (const float*)d_in[0];
  const int*   ei = (const int*)d_in[1];
  const float* W1 = (const float*)d_in[3];
  const float* b1 = (const float*)d_in[4];
  const float* W2 = (const float*)d_in[5];
  const float* b2 = (const float*)d_in[6];

  const int N   = in_sizes[2];          // 10000
  const int E   = in_sizes[1] / 2;      // 320000
  const int Fin = in_sizes[0] / N;      // 512
  const int F1  = in_sizes[4];          // 256
  const int F2  = in_sizes[6];          // 128

  const int* src = ei;
  const int* dst = ei + E;

  float* ws = (float*)d_ws;
  ushort* w1t      = (ushort*)ws;                    // F1*Fin ush = 65,536 f
  ushort* w2t      = (ushort*)(ws + 65536);          // F2*F1 ush = 16,384 f
  ushort* xb       = (ushort*)(ws + 81920);          // N*Fin ush = 2,560,000 f
  ushort* h1b      = (ushort*)(ws + 2641920);        // N*F1 ush = 1,280,000 f
  ushort* agg1b    = (ushort*)(ws + 3921920);        // N*F1 ush = 1,280,000 f
  ushort* h2b      = (ushort*)(ws + 5201920);        // N*F2 ush = 640,000 f
  ushort* hb       = (ushort*)(ws + 5841920);        // N*F2 ush = 640,000 f
  float*  dinv     = ws + 6481920;                   // N (pad 10240)
  int*    cnt      = (int*)(ws + 6492160);           // N
  int*    cursor   = (int*)(ws + 6502400);           // N
  int*    rowstart = (int*)(ws + 6512640);           // N+1 (pad 10496)
  int*    esrc     = (int*)(ws + 6523136);           // E

  float* out_x1 = (float*)d_out;
  float* out_h  = out_x1 + (long)N * N;

  // CSR build + dinv
  k_zero_i<<<(N + 255) / 256, 256, 0, stream>>>(cnt, N);
  k_count<<<(E + 255) / 256, 256, 0, stream>>>(dst, cnt, E);
  k_scan<<<1, 1024, 0, stream>>>(cnt, rowstart, cursor, dinv, N, E);
  k_csr<<<(E + 255) / 256, 256, 0, stream>>>(src, dst, cursor, esrc, E);

  // conversions: weights (transposed bf16) and x (bf16)
  {
    int tot = Fin * F1 + F1 * F2;
    k_wt<<<(tot + 255) / 256, 256, 0, stream>>>(W1, w1t, Fin, F1, W2, w2t, F1, F2);
    long xtot = (long)N * Fin;
    k_xb<<<(unsigned)((xtot / 4 + 255) / 256), 256, 0, stream>>>(x, xb, xtot);
  }

  // layer 1: h1b = bf16( x @ W1 ), K = 512, BM=64 (314 blocks)
  {
    dim3 grid(F1 / 128, (N + 63) / 64);
    k_gemm_bt<64><<<grid, 256, 0, stream>>>(xb, w1t, h1b, N, F1, Fin, F1);
  }
  k_agg<256, 4, false><<<N, 64, 0, stream>>>(h1b, dinv, rowstart, esrc, b1,
                                             agg1b, nullptr, N);

  // layer 2: h2b = bf16( agg1 @ W2 ), K = 256, BM=64 (157 blocks)
  {
    dim3 grid(F2 / 128, (N + 63) / 64);
    k_gemm_bt<64><<<grid, 256, 0, stream>>>(agg1b, w2t, h2b, N, F2, F1, F2);
  }
  k_agg<128, 2, true><<<N, 64, 0, stream>>>(h2b, dinv, rowstart, esrc, b2,
                                            hb, out_h, N);

  // decode: x1 = sigmoid(h @ h^T), symmetric triangular grid
  {
    int NB = (N + 127) / 128;
    int nblk = NB * (NB + 1) / 2;
    k_decode_sym<<<nblk, 256, 0, stream>>>(hb, out_x1, N);
  }
}

// Round 11
// 248.271 us; speedup vs baseline: 1.4841x; 1.0168x over previous
//
#include <hip/hip_runtime.h>
#include <math.h>

#define LEAKY 0.01f

using short8   = __attribute__((ext_vector_type(8))) short;
using f32x4    = __attribute__((ext_vector_type(4))) float;
using ushort4e = __attribute__((ext_vector_type(4))) unsigned short;

__device__ __forceinline__ ushort f2bf(float f) {
  uint u = __float_as_uint(f);
  uint r = (u + 0x7FFFu + ((u >> 16) & 1u)) >> 16;
  return (ushort)r;
}
__device__ __forceinline__ float bf2f(ushort h) {
  uint u = ((uint)h) << 16;
  return __uint_as_float(u);
}

// ---------------- degree / CSR build ----------------

__global__ void k_count(const int* __restrict__ dst, int* __restrict__ cnt, int E) {
  int i = blockIdx.x * blockDim.x + threadIdx.x;
  if (i < E) atomicAdd(&cnt[dst[i]], 1);
}

// single block, 1024 threads; N <= 16384. Also emits dinv = rsqrt(cnt+1).
__global__ void k_scan(const int* __restrict__ cnt, int* __restrict__ rowstart,
                       int* __restrict__ cursor, float* __restrict__ dinv,
                       int N, int Etot) {
  __shared__ int part[1024];
  const int t = threadIdx.x;
  const int CH = 16;
  int base = t * CH;
  int local[CH];
  int s = 0;
#pragma unroll
  for (int i = 0; i < CH; i++) {
    int v = (base + i < N) ? cnt[base + i] : 0;
    if (base + i < N) dinv[base + i] = rsqrtf((float)v + 1.0f);
    local[i] = s;
    s += v;
  }
  part[t] = s;
  __syncthreads();
  for (int off = 1; off < 1024; off <<= 1) {
    int add = (t >= off) ? part[t - off] : 0;
    __syncthreads();
    part[t] += add;
    __syncthreads();
  }
  int excl = (t == 0) ? 0 : part[t - 1];
#pragma unroll
  for (int i = 0; i < CH; i++) {
    if (base + i < N) {
      int rs = excl + local[i];
      rowstart[base + i] = rs;
      cursor[base + i] = rs;
    }
  }
  if (t == 0) rowstart[N] = Etot;
}

// CSR fill + per-edge norm precompute
__global__ void k_csr(const int* __restrict__ src, const int* __restrict__ dst,
                      const float* __restrict__ dinv, int* __restrict__ cursor,
                      int* __restrict__ esrc, float* __restrict__ enorm, int E) {
  int i = blockIdx.x * blockDim.x + threadIdx.x;
  if (i < E) {
    int d = dst[i];
    int s = src[i];
    int pos = atomicAdd(&cursor[d], 1);
    esrc[pos] = s;
    enorm[pos] = dinv[s] * dinv[d];
  }
}

// ---------------- prep: x -> bf16 and W1/W2 -> transposed bf16, one launch ----------------
__global__ void k_prep(const float* __restrict__ X, ushort* __restrict__ Xb, long xq,
                       const float* __restrict__ W1, ushort* __restrict__ Wt1,
                       int K1, int N1,
                       const float* __restrict__ W2, ushort* __restrict__ Wt2,
                       int K2, int N2) {
  long i = (long)blockIdx.x * blockDim.x + threadIdx.x;
  if (i < xq) {
    long b = i * 4;
    float4 v = *reinterpret_cast<const float4*>(&X[b]);
    ushort4e u = {f2bf(v.x), f2bf(v.y), f2bf(v.z), f2bf(v.w)};
    *reinterpret_cast<ushort4e*>(&Xb[b]) = u;
  } else {
    long j = i - xq;
    int t1 = K1 * N1;
    if (j < t1) {
      int k = (int)(j / N1), n = (int)(j % N1);
      Wt1[(long)n * K1 + k] = f2bf(W1[j]);
    } else if (j < t1 + (long)K2 * N2) {
      long jj = j - t1;
      int k = (int)(jj / N2), n = (int)(jj % N2);
      Wt2[(long)n * K2 + k] = f2bf(W2[jj]);
    }
  }
}

// ---------------- gather aggregation: bf16 in/out, precomputed edge norms ----------------
// WAVES waves per node; each wave owns F/WAVES feats, VL=2 per lane (4B loads).
template <int F, int WAVES, bool LAST>
__global__ __launch_bounds__(64 * WAVES) void k_agg(const ushort* __restrict__ hlin,
                                                    const float* __restrict__ dinv,
                                                    const int* __restrict__ rowstart,
                                                    const int* __restrict__ esrc,
                                                    const float* __restrict__ enorm,
                                                    const float* __restrict__ bias,
                                                    ushort* __restrict__ aggb,
                                                    float* __restrict__ outh, int N) {
  constexpr int FS = F / WAVES;   // feats per wave (=128)
  const int node = blockIdx.x;
  const int tid = threadIdx.x;
  const int w = tid >> 6;
  const int lane = tid & 63;
  const int f0 = w * FS + lane * 2;
  const float di = dinv[node];

  float acc0, acc1;
  {
    uint v = *reinterpret_cast<const uint*>(&hlin[(long)node * F + f0]);
    float dd = di * di;
    acc0 = bf2f((ushort)(v & 0xffff)) * dd;
    acc1 = bf2f((ushort)(v >> 16)) * dd;
  }
  const int e0 = rowstart[node], e1 = rowstart[node + 1];
  int e = e0;
  for (; e + 7 < e1; e += 8) {
#pragma unroll
    for (int u = 0; u < 8; u++) {
      int s = esrc[e + u];
      float nm = enorm[e + u];
      uint v = *reinterpret_cast<const uint*>(&hlin[(long)s * F + f0]);
      acc0 += bf2f((ushort)(v & 0xffff)) * nm;
      acc1 += bf2f((ushort)(v >> 16)) * nm;
    }
  }
  for (; e < e1; e++) {
    int s = esrc[e];
    float nm = enorm[e];
    uint v = *reinterpret_cast<const uint*>(&hlin[(long)s * F + f0]);
    acc0 += bf2f((ushort)(v & 0xffff)) * nm;
    acc1 += bf2f((ushort)(v >> 16)) * nm;
  }

  float v0 = acc0 + bias[f0];
  float v1 = acc1 + bias[f0 + 1];
  v0 = (v0 > 0.f) ? v0 : (LEAKY * v0);
  v1 = (v1 > 0.f) ? v1 : (LEAKY * v1);
  uint o = (uint)f2bf(v0) | ((uint)f2bf(v1) << 16);
  *reinterpret_cast<uint*>(&aggb[(long)node * F + f0]) = o;
  if constexpr (LAST) {
    float2 fo = make_float2(v0, v1);
    *reinterpret_cast<float2*>(&outh[(long)node * F + f0]) = fo;
  }
}

// ---------------- bf16 MFMA GEMM-BT, templated BM, bf16 out ----------------
// C[M,N] = A[M,K] * B[N,K]^T, A/B bf16 row-major, K mult of 128.
template <int BM>
__global__ __launch_bounds__(256) void k_gemm_bt(const ushort* __restrict__ Ab,
                                                 const ushort* __restrict__ Bb,
                                                 ushort* __restrict__ Cb,
                                                 int M, int N, int K, int ldc) {
  constexpr int MI = BM / 32;
  __shared__ __align__(16) ushort lds[(BM + 128) * 128];
  ushort* ldsA = lds;
  ushort* ldsB = lds + BM * 128;

  const int tid = threadIdx.x;
  const int lane = tid & 63;
  const int wv = tid >> 6;
  const int wr = wv >> 1, wc = wv & 1;
  const long bm = (long)blockIdx.y * BM;
  const long bn = (long)blockIdx.x * 128;

  f32x4 acc[MI][4];
#pragma unroll
  for (int i = 0; i < MI; i++)
#pragma unroll
    for (int j = 0; j < 4; j++) acc[i][j] = (f32x4){0.f, 0.f, 0.f, 0.f};

  const int kb = ((lane >> 4) << 4);

  for (int k0 = 0; k0 < K; k0 += 128) {
#pragma unroll
    for (int it = 0; it < BM / 16; it++) {
      int off = it * 4096 + tid * 16;
      int row = off >> 8;
      int cb = off & 255;
      long gr = bm + row;
      uint4 v = make_uint4(0u, 0u, 0u, 0u);
      if (gr < M) v = *reinterpret_cast<const uint4*>(&Ab[gr * K + k0 + (cb >> 1)]);
      int sb = (row << 8) | (cb ^ ((row & 7) << 4));
      *reinterpret_cast<uint4*>((char*)ldsA + sb) = v;
    }
#pragma unroll
    for (int it = 0; it < 8; it++) {
      int off = it * 4096 + tid * 16;
      int row = off >> 8;
      int cb = off & 255;
      long gn = bn + row;
      uint4 v = make_uint4(0u, 0u, 0u, 0u);
      if (gn < N) v = *reinterpret_cast<const uint4*>(&Bb[gn * K + k0 + (cb >> 1)]);
      int sb = (row << 8) | (cb ^ ((row & 7) << 4));
      *reinterpret_cast<uint4*>((char*)ldsB + sb) = v;
    }
    __syncthreads();

#pragma unroll
    for (int ks = 0; ks < 4; ks++) {
      short8 af[MI], bfr[4];
#pragma unroll
      for (int mi = 0; mi < MI; mi++) {
        int row = wr * (BM / 2) + mi * 16 + (lane & 15);
        int b = ks * 64 + kb;
        int addr = (row << 8) | (b ^ ((row & 7) << 4));
        af[mi] = *reinterpret_cast<const short8*>((const char*)ldsA + addr);
      }
#pragma unroll
      for (int ni = 0; ni < 4; ni++) {
        int row = wc * 64 + ni * 16 + (lane & 15);
        int b = ks * 64 + kb;
        int addr = (row << 8) | (b ^ ((row & 7) << 4));
        bfr[ni] = *reinterpret_cast<const short8*>((const char*)ldsB + addr);
      }
#pragma unroll
      for (int mi = 0; mi < MI; mi++)
#pragma unroll
        for (int ni = 0; ni < 4; ni++)
          acc[mi][ni] = __builtin_amdgcn_mfma_f32_16x16x32_bf16(af[mi], bfr[ni], acc[mi][ni], 0, 0, 0);
    }
    __syncthreads();
  }

#pragma unroll
  for (int ni = 0; ni < 4; ni++) {
    long col = bn + wc * 64 + ni * 16 + (lane & 15);
    if (col >= N) continue;
#pragma unroll
    for (int mi = 0; mi < MI; mi++) {
      long rbase2 = bm + wr * (BM / 2) + mi * 16 + ((lane >> 4) << 2);
#pragma unroll
      for (int j = 0; j < 4; j++) {
        long row = rbase2 + j;
        if (row >= M) continue;
        Cb[row * ldc + col] = f2bf(acc[mi][ni][j]);
      }
    }
  }
}

// ---------------- symmetric decode: x1 = sigmoid(H H^T), H [N,128] bf16 ----------------
// Triangular grid. NT stores with full-64B-line coverage per instruction (R6/R8 lesson).
__global__ __launch_bounds__(256) void k_decode_sym(const ushort* __restrict__ Hb,
                                                    float* __restrict__ C, int N) {
  __shared__ __align__(16) ushort lds[2 * 128 * 128];
  ushort* ldsA = lds;
  ushort* ldsB = lds + 128 * 128;

  const int tid = threadIdx.x;
  const int lane = tid & 63;
  const int wv = tid >> 6;
  const int wr = wv >> 1, wc = wv & 1;

  int t = blockIdx.x;
  int bi = (int)((sqrtf(8.f * (float)t + 1.f) - 1.f) * 0.5f);
  while ((bi + 1) * (bi + 2) / 2 <= t) bi++;
  while (bi * (bi + 1) / 2 > t) bi--;
  int bj = t - bi * (bi + 1) / 2;
  const long bm = (long)bi * 128;
  const long bn = (long)bj * 128;

#pragma unroll
  for (int s = 0; s < 2; s++) {
    long rbase = s ? bn : bm;
    ushort* L = s ? ldsB : ldsA;
#pragma unroll
    for (int it = 0; it < 8; it++) {
      int off = it * 4096 + tid * 16;
      int row = off >> 8;
      int cb = off & 255;
      long grow = rbase + row;
      uint4 v = make_uint4(0u, 0u, 0u, 0u);
      if (grow < N)
        v = *reinterpret_cast<const uint4*>(&Hb[grow * 128 + (cb >> 1)]);
      int sb = (row << 8) | (cb ^ ((row & 7) << 4));
      *reinterpret_cast<uint4*>((char*)L + sb) = v;
    }
  }
  __syncthreads();

  f32x4 acc[4][4];
#pragma unroll
  for (int i = 0; i < 4; i++)
#pragma unroll
    for (int j = 0; j < 4; j++) acc[i][j] = (f32x4){0.f, 0.f, 0.f, 0.f};

  const int kb = ((lane >> 4) << 4);
#pragma unroll
  for (int ks = 0; ks < 4; ks++) {
    short8 af[4], bfr[4];
#pragma unroll
    for (int mi = 0; mi < 4; mi++) {
      int row = wr * 64 + mi * 16 + (lane & 15);
      int b = ks * 64 + kb;
      int addr = (row << 8) | (b ^ ((row & 7) << 4));
      af[mi] = *reinterpret_cast<const short8*>((const char*)ldsA + addr);
    }
#pragma unroll
    for (int ni = 0; ni < 4; ni++) {
      int row = wc * 64 + ni * 16 + (lane & 15);
      int b = ks * 64 + kb;
      int addr = (row << 8) | (b ^ ((row & 7) << 4));
      bfr[ni] = *reinterpret_cast<const short8*>((const char*)ldsB + addr);
    }
#pragma unroll
    for (int mi = 0; mi < 4; mi++)
#pragma unroll
      for (int ni = 0; ni < 4; ni++)
        acc[mi][ni] = __builtin_amdgcn_mfma_f32_16x16x32_bf16(af[mi], bfr[ni], acc[mi][ni], 0, 0, 0);
  }

  // sigmoid once in registers
#pragma unroll
  for (int mi = 0; mi < 4; mi++)
#pragma unroll
    for (int ni = 0; ni < 4; ni++)
#pragma unroll
      for (int j = 0; j < 4; j++)
        acc[mi][ni][j] = __builtin_amdgcn_rcpf(1.f + __expf(-acc[mi][ni][j]));

  // transposed store direct from registers: 16 full 64B lines per instr
  if (bi != bj) {
#pragma unroll
    for (int ni = 0; ni < 4; ni++) {
      long gr = bn + wc * 64 + ni * 16 + (lane & 15);
#pragma unroll
      for (int mi = 0; mi < 4; mi++) {
        long gc = bm + wr * 64 + mi * 16 + ((lane >> 4) << 2);
        if (gr < N && gc < N)
          __builtin_nontemporal_store(acc[mi][ni],
                                      reinterpret_cast<f32x4*>(&C[gr * N + gc]));
      }
    }
  }

  __syncthreads();

  // normal orientation via LDS bounce, coalesced 512B rows
  float* ft = (float*)lds;
#pragma unroll
  for (int ni = 0; ni < 4; ni++) {
    int col = wc * 64 + ni * 16 + (lane & 15);
#pragma unroll
    for (int mi = 0; mi < 4; mi++) {
      int rb = wr * 64 + mi * 16 + ((lane >> 4) << 2);
#pragma unroll
      for (int j = 0; j < 4; j++) {
        int row = rb + j;
        int byte = (row << 9) + (col << 2);
        byte ^= ((row & 7) << 4);
        *reinterpret_cast<float*>((char*)ft + byte) = acc[mi][ni][j];
      }
    }
  }
  __syncthreads();

#pragma unroll
  for (int it = 0; it < 16; it++) {
    int r = (tid >> 5) + it * 8;
    int ch = tid & 31;
    int byte = (r << 9) + (ch << 4);
    byte ^= ((r & 7) << 4);
    f32x4 v = *reinterpret_cast<const f32x4*>((const char*)ft + byte);
    long gr = bm + r;
    long gc = bn + ch * 4;
    if (gr < N && gc < N)
      __builtin_nontemporal_store(v, reinterpret_cast<f32x4*>(&C[gr * N + gc]));
  }
}

// ---------------- launch ----------------

extern "C" void kernel_launch(void* const* d_in, const int* in_sizes, int n_in,
                              void* d_out, int out_size, void* d_ws, size_t ws_size,
                              hipStream_t stream) {
  const float* x  = (const float*)d_in[0];
  const int*   ei = (const int*)d_in[1];
  const float* W1 = (const float*)d_in[3];
  const float* b1 = (const float*)d_in[4];
  const float* W2 = (const float*)d_in[5];
  const float* b2 = (const float*)d_in[6];

  const int N   = in_sizes[2];          // 10000
  const int E   = in_sizes[1] / 2;      // 320000
  const int Fin = in_sizes[0] / N;      // 512
  const int F1  = in_sizes[4];          // 256
  const int F2  = in_sizes[6];          // 128

  const int* src = ei;
  const int* dst = ei + E;

  float* ws = (float*)d_ws;
  ushort* w1t      = (ushort*)ws;                    // F1*Fin ush = 65,536 f
  ushort* w2t      = (ushort*)(ws + 65536);          // F2*F1 ush = 16,384 f
  ushort* xb       = (ushort*)(ws + 81920);          // N*Fin ush = 2,560,000 f
  ushort* h1b      = (ushort*)(ws + 2641920);        // N*F1 ush = 1,280,000 f
  ushort* agg1b    = (ushort*)(ws + 3921920);        // N*F1 ush = 1,280,000 f
  ushort* h2b      = (ushort*)(ws + 5201920);        // N*F2 ush = 640,000 f
  ushort* hb       = (ushort*)(ws + 5841920);        // N*F2 ush = 640,000 f
  float*  dinv     = ws + 6481920;                   // N (pad 10240)
  int*    cnt      = (int*)(ws + 6492160);           // N
  int*    cursor   = (int*)(ws + 6502400);           // N
  int*    rowstart = (int*)(ws + 6512640);           // N+1 (pad 10496)
  int*    esrc     = (int*)(ws + 6523136);           // E
  float*  enorm    = ws + 6843136;                   // E

  float* out_x1 = (float*)d_out;
  float* out_h  = out_x1 + (long)N * N;

  // CSR build + dinv (cnt zeroed via memset — graph-capturable)
  hipMemsetAsync(cnt, 0, (size_t)N * sizeof(int), stream);
  k_count<<<(E + 255) / 256, 256, 0, stream>>>(dst, cnt, E);
  k_scan<<<1, 1024, 0, stream>>>(cnt, rowstart, cursor, dinv, N, E);
  k_csr<<<(E + 255) / 256, 256, 0, stream>>>(src, dst, dinv, cursor, esrc, enorm, E);

  // conversions: x -> bf16, W1/W2 -> transposed bf16 (single launch)
  {
    long xq = (long)N * Fin / 4;
    long tot = xq + (long)Fin * F1 + (long)F1 * F2;
    k_prep<<<(unsigned)((tot + 255) / 256), 256, 0, stream>>>(
        x, xb, xq, W1, w1t, Fin, F1, W2, w2t, F1, F2);
  }

  // layer 1: h1b = bf16( x @ W1 ), K = 512, BM=64 (314 blocks)
  {
    dim3 grid(F1 / 128, (N + 63) / 64);
    k_gemm_bt<64><<<grid, 256, 0, stream>>>(xb, w1t, h1b, N, F1, Fin, F1);
  }
  // agg1: 2 waves/node over 256 feats
  k_agg<256, 2, false><<<N, 128, 0, stream>>>(h1b, dinv, rowstart, esrc, enorm, b1,
                                              agg1b, nullptr, N);

  // layer 2: h2b = bf16( agg1 @ W2 ), K = 256, BM=64 (157 blocks)
  {
    dim3 grid(F2 / 128, (N + 63) / 64);
    k_gemm_bt<64><<<grid, 256, 0, stream>>>(agg1b, w2t, h2b, N, F2, F1, F2);
  }
  // agg2: 1 wave/node over 128 feats; writes bf16 hb + fp32 out_h
  k_agg<128, 1, true><<<N, 64, 0, stream>>>(h2b, dinv, rowstart, esrc, enorm, b2,
                                            hb, out_h, N);

  // decode: x1 = sigmoid(h @ h^T), symmetric triangular grid
  {
    int NB = (N + 127) / 128;
    int nblk = NB * (NB + 1) / 2;
    k_decode_sym<<<nblk, 256, 0, stream>>>(hb, out_x1, N);
  }
}